// Round 1
// baseline (16017.404 us; speedup 1.0000x reference)
//
#include <hip/hip_runtime.h>

// Bidirectional GRU, T=512, B=64, I=512, H=512, fp32.
// out layout: [T][B][2H] (fwd j in [0,H), bwd j in [H,2H)) then hT_f [B][H], hT_b [B][H].
// Step s: fwd t=s reads h_prev from out[t-1][:,0:H] (h0_fwd at s=0);
//         bwd t=T-1-s reads h_prev from out[t+1][:,H:2H] (h0_bwd at s=0).
// One kernel launch per step; both directions in one grid (blockIdx.y).

#define TT 512
#define BB 64
#define II 512
#define HH 512

__global__ __launch_bounds__(256) void gru_step_kernel(
    const float* __restrict__ inp,
    const float* __restrict__ h0f, const float* __restrict__ h0b,
    const float* __restrict__ Wih_f, const float* __restrict__ Whh_f,
    const float* __restrict__ bih_f, const float* __restrict__ bhh_f,
    const float* __restrict__ Wih_b, const float* __restrict__ Whh_b,
    const float* __restrict__ bih_b, const float* __restrict__ bhh_b,
    float* __restrict__ out, int s)
{
    const int dir  = blockIdx.y;          // 0 = fwd, 1 = bwd
    const int jblk = blockIdx.x;          // 128 blocks of 4 j each
    const int tid  = threadIdx.x;         // 256 threads: b = tid>>2, jj = tid&3
    const int b    = tid >> 2;
    const int jj   = tid & 3;
    const int j    = (jblk << 2) | jj;

    const int t = dir ? (TT - 1 - s) : s;
    const float* Wih = dir ? Wih_b : Wih_f;
    const float* Whh = dir ? Whh_b : Whh_f;
    const float* bih = dir ? bih_b : bih_f;
    const float* bhh = dir ? bhh_b : bhh_f;

    const float* xrow = inp + (size_t)t * (BB * II);   // [B][I] slice at time t

    const float* hp;      // h_prev base: hp[b*hstride + k]
    int hstride;
    if (s == 0) {
        hp = dir ? h0b : h0f;
        hstride = HH;
    } else {
        const int tp = dir ? (t + 1) : (t - 1);
        hp = out + (size_t)tp * (BB * 2 * HH) + dir * HH;
        hstride = 2 * HH;
    }

    // LDS tiles. Inner dim padded to 36 floats: keeps 16B alignment for float4
    // stores and rotates banks by 4 per row (b vs b+8 is a free 2-way conflict).
    __shared__ float xs[BB][36];
    __shared__ float hs[BB][36];
    __shared__ float ws[24][36];   // rows: gate g (0..5: ir,iz,in,hr,hz,hn) * 4 + j_local

    float acc0 = 0.f, acc1 = 0.f, acc2 = 0.f, acc3 = 0.f, acc4 = 0.f, acc5 = 0.f;

    for (int k0 = 0; k0 < II; k0 += 32) {
        __syncthreads();
        // Stage x chunk [64][32] and h chunk [64][32]: 512 float4 slots each, 2 per thread.
        #pragma unroll
        for (int v = 0; v < 2; ++v) {
            const int slot = tid + v * 256;        // 0..511
            const int r = slot >> 3;               // row 0..63
            const int c = (slot & 7) << 2;         // col 0,4,..,28
            *(float4*)&xs[r][c] = *(const float4*)&xrow[r * II + k0 + c];
            *(float4*)&hs[r][c] = *(const float4*)&hp[r * hstride + k0 + c];
        }
        // Stage 24 weight rows (6 gates x 4 local j) x 32 k: 192 float4 slots.
        if (tid < 192) {
            const int row = tid >> 3;              // 0..23
            const int c   = (tid & 7) << 2;
            const int g   = row >> 2;              // 0..5
            const int jl  = row & 3;
            const int jg  = (jblk << 2) | jl;
            const float* W = (g < 3) ? Wih : Whh;
            const int wrow = ((g < 3) ? g : (g - 3)) * HH + jg;
            *(float4*)&ws[row][c] = *(const float4*)&W[(size_t)wrow * II + k0 + c];
        }
        __syncthreads();

        #pragma unroll
        for (int k = 0; k < 32; ++k) {
            const float xv = xs[b][k];
            const float hv = hs[b][k];
            acc0 += xv * ws[jj     ][k];
            acc1 += xv * ws[jj +  4][k];
            acc2 += xv * ws[jj +  8][k];
            acc3 += hv * ws[jj + 12][k];
            acc4 += hv * ws[jj + 16][k];
            acc5 += hv * ws[jj + 20][k];
        }
    }

    const float ir  = acc0 + bih[j];
    const float iz  = acc1 + bih[HH + j];
    const float in_ = acc2 + bih[2 * HH + j];
    const float hr  = acc3 + bhh[j];
    const float hz  = acc4 + bhh[HH + j];
    const float hn  = acc5 + bhh[2 * HH + j];

    const float r = 1.f / (1.f + __expf(-(ir + hr)));
    const float z = 1.f / (1.f + __expf(-(iz + hz)));
    const float n = tanhf(in_ + r * hn);

    const float hprev = hp[b * hstride + j];
    const float hnew  = (1.f - z) * n + z * hprev;

    out[(size_t)t * (BB * 2 * HH) + b * (2 * HH) + dir * HH + j] = hnew;

    if (s == TT - 1) {
        float* hT = out + (size_t)TT * BB * 2 * HH + dir * (BB * HH);
        hT[b * HH + j] = hnew;
    }
}

extern "C" void kernel_launch(void* const* d_in, const int* in_sizes, int n_in,
                              void* d_out, int out_size, void* d_ws, size_t ws_size,
                              hipStream_t stream) {
    (void)in_sizes; (void)n_in; (void)d_ws; (void)ws_size; (void)out_size;

    const float* inp   = (const float*)d_in[0];
    const float* h0f   = (const float*)d_in[1];
    const float* h0b   = (const float*)d_in[2];
    const float* Wih_f = (const float*)d_in[3];
    const float* Whh_f = (const float*)d_in[4];
    const float* bih_f = (const float*)d_in[5];
    const float* bhh_f = (const float*)d_in[6];
    const float* Wih_b = (const float*)d_in[7];
    const float* Whh_b = (const float*)d_in[8];
    const float* bih_b = (const float*)d_in[9];
    const float* bhh_b = (const float*)d_in[10];
    float* out = (float*)d_out;

    const dim3 grid(HH / 4, 2, 1);   // 128 j-blocks x 2 directions
    const dim3 block(256, 1, 1);

    for (int s = 0; s < TT; ++s) {
        gru_step_kernel<<<grid, block, 0, stream>>>(
            inp, h0f, h0b,
            Wih_f, Whh_f, bih_f, bhh_f,
            Wih_b, Whh_b, bih_b, bhh_b,
            out, s);
    }
}

// Round 2
// 7650.119 us; speedup vs baseline: 2.0937x; 2.0937x over previous
//
#include <hip/hip_runtime.h>

// Bidirectional GRU, T=512, B=64, I=512, H=512, fp32 in/out.
// out layout: [T][B][2H] (fwd j in [0,H), bwd j in [H,2H)), then hT_f [B][H], hT_b [B][H].
// Step s: fwd t=s reads h_prev from out[t-1][:,0:H]; bwd t=T-1-s from out[t+1][:,H:2H].
// Per-step GEMM done with v_mfma_f32_16x16x32_bf16, fragments loaded straight from
// global (no LDS): A = x/h rows (fp32 -> bf16 inline), B = weight rows (bf16 in d_ws
// if it fits, else fp32 inline-converted). n-gate keeps separate i_n / h_n accs.

#define TT 512
#define BB 64
#define II 512
#define HH 512

typedef __attribute__((ext_vector_type(8))) short short8;
typedef __attribute__((ext_vector_type(4))) float f32x4;

static __device__ __forceinline__ short f2bf(float f) {
    union { float f; unsigned int u; } v; v.f = f;
    unsigned int r = (v.u + 0x7fffu + ((v.u >> 16) & 1u)) >> 16;  // RNE
    return (short)r;
}

// load 8 contiguous fp32, convert to bf16x8 fragment
static __device__ __forceinline__ short8 ldcvt(const float* __restrict__ p) {
    const float4 a = *(const float4*)p;
    const float4 b = *(const float4*)(p + 4);
    short8 r;
    r[0] = f2bf(a.x); r[1] = f2bf(a.y); r[2] = f2bf(a.z); r[3] = f2bf(a.w);
    r[4] = f2bf(b.x); r[5] = f2bf(b.y); r[6] = f2bf(b.z); r[7] = f2bf(b.w);
    return r;
}

static __device__ __forceinline__ short8 ldbf(const unsigned short* __restrict__ p) {
    return *(const short8*)p;  // 16 B
}

// Pack weights to bf16 in ws: layout [dir][gate][j][k] with k in [0,1024):
// k<512 -> Wih[g*H+j][k], k>=512 -> Whh[g*H+j][k-512]. 6.29 MB total.
__global__ __launch_bounds__(256) void convert_w_kernel(
    const float* __restrict__ Wih_f, const float* __restrict__ Whh_f,
    const float* __restrict__ Wih_b, const float* __restrict__ Whh_b,
    unsigned short* __restrict__ wsW)
{
    const int total4 = 2 * 3 * HH * 1024 / 4;  // float4-granular
    for (int i = blockIdx.x * 256 + threadIdx.x; i < total4; i += gridDim.x * 256) {
        const int e   = i * 4;
        const int k   = e & 1023;
        const int row = e >> 10;          // 0..3071
        const int dir = row / 1536;
        const int rem = row - dir * 1536;
        const int g   = rem >> 9;         // 0..2
        const int j   = rem & 511;
        const float* W = (k < 512) ? (dir ? Wih_b : Wih_f) : (dir ? Whh_b : Whh_f);
        const int kk = k & 511;
        const float4 v = *(const float4*)&W[(size_t)(g * HH + j) * II + kk];
        unsigned short o[4] = { (unsigned short)f2bf(v.x), (unsigned short)f2bf(v.y),
                                (unsigned short)f2bf(v.z), (unsigned short)f2bf(v.w) };
        *(ushort4*)&wsW[e] = *(ushort4*)o;
    }
}

template <bool USE_WS>
__global__ __launch_bounds__(64) void gru_step_kernel(
    const float* __restrict__ inp,
    const float* __restrict__ h0f, const float* __restrict__ h0b,
    const float* __restrict__ Wih_f, const float* __restrict__ Whh_f,
    const float* __restrict__ bih_f, const float* __restrict__ bhh_f,
    const float* __restrict__ Wih_b, const float* __restrict__ Whh_b,
    const float* __restrict__ bih_b, const float* __restrict__ bhh_b,
    const unsigned short* __restrict__ wsW,
    float* __restrict__ out, int s)
{
    const int jt   = blockIdx.x;   // 0..31  (j tile of 16)
    const int mt   = blockIdx.y;   // 0..3   (batch tile of 16)
    const int dir  = blockIdx.z;   // 0 fwd, 1 bwd
    const int lane = threadIdx.x;  // 64
    const int nm   = lane & 15;
    const int kq   = lane >> 4;
    const int j0   = jt * 16;
    const int koff = kq * 8;

    const int t  = dir ? (TT - 1 - s) : s;
    const int tp = dir ? (t + 1) : (t - 1);

    const float* Wih = dir ? Wih_b : Wih_f;
    const float* Whh = dir ? Whh_b : Whh_f;
    const float* bih = dir ? bih_b : bih_f;
    const float* bhh = dir ? bhh_b : bhh_f;
    const float* h0  = dir ? h0b : h0f;

    const int arow = mt * 16 + nm;  // batch row this lane loads for A frags

    const float* xrow = inp + ((size_t)t * BB + arow) * II;
    const float* hrow = (s == 0) ? (h0 + (size_t)arow * HH)
                                 : (out + ((size_t)tp * BB + arow) * 2 * HH + dir * HH);

    // B fragment row bases (row = gate row j0+nm, contiguous k)
    const unsigned short* wb0 = nullptr; const unsigned short* wb1 = nullptr;
    const unsigned short* wb2 = nullptr;
    if (USE_WS) {
        const size_t base = ((size_t)(dir * 3 + 0) * HH + (j0 + nm)) * 1024;
        wb0 = wsW + base;
        wb1 = wsW + base + (size_t)HH * 1024;
        wb2 = wsW + base + (size_t)2 * HH * 1024;
    }
    const float* wi0 = Wih + (size_t)(0 * HH + j0 + nm) * II;
    const float* wi1 = Wih + (size_t)(1 * HH + j0 + nm) * II;
    const float* wi2 = Wih + (size_t)(2 * HH + j0 + nm) * II;
    const float* wh0 = Whh + (size_t)(0 * HH + j0 + nm) * II;
    const float* wh1 = Whh + (size_t)(1 * HH + j0 + nm) * II;
    const float* wh2 = Whh + (size_t)(2 * HH + j0 + nm) * II;

    f32x4 ar  = {0.f, 0.f, 0.f, 0.f};
    f32x4 az  = ar, ain = ar, ahn = ar;

    // x half: K = I, gates r, z, i_n
    #pragma unroll 4
    for (int k0 = 0; k0 < II; k0 += 32) {
        const int kk = k0 + koff;
        const short8 a  = ldcvt(xrow + kk);
        const short8 b0 = USE_WS ? ldbf(wb0 + kk) : ldcvt(wi0 + kk);
        const short8 b1 = USE_WS ? ldbf(wb1 + kk) : ldcvt(wi1 + kk);
        const short8 b2 = USE_WS ? ldbf(wb2 + kk) : ldcvt(wi2 + kk);
        ar  = __builtin_amdgcn_mfma_f32_16x16x32_bf16(a, b0, ar, 0, 0, 0);
        az  = __builtin_amdgcn_mfma_f32_16x16x32_bf16(a, b1, az, 0, 0, 0);
        ain = __builtin_amdgcn_mfma_f32_16x16x32_bf16(a, b2, ain, 0, 0, 0);
    }
    // h half: K = H, gates r, z, h_n
    #pragma unroll 4
    for (int k0 = 0; k0 < HH; k0 += 32) {
        const int kk = k0 + koff;
        const short8 a  = ldcvt(hrow + kk);
        const short8 b0 = USE_WS ? ldbf(wb0 + 512 + kk) : ldcvt(wh0 + kk);
        const short8 b1 = USE_WS ? ldbf(wb1 + 512 + kk) : ldcvt(wh1 + kk);
        const short8 b2 = USE_WS ? ldbf(wb2 + 512 + kk) : ldcvt(wh2 + kk);
        ar  = __builtin_amdgcn_mfma_f32_16x16x32_bf16(a, b0, ar, 0, 0, 0);
        az  = __builtin_amdgcn_mfma_f32_16x16x32_bf16(a, b1, az, 0, 0, 0);
        ahn = __builtin_amdgcn_mfma_f32_16x16x32_bf16(a, b2, ahn, 0, 0, 0);
    }

    // Epilogue. C/D layout: col(j) = lane&15, row(b) = (lane>>4)*4 + reg.
    const int jg = j0 + nm;
    const float b_ir = bih[jg], b_iz = bih[HH + jg], b_in = bih[2 * HH + jg];
    const float b_hr = bhh[jg], b_hz = bhh[HH + jg], b_hn = bhh[2 * HH + jg];

    #pragma unroll
    for (int rg = 0; rg < 4; ++rg) {
        const int be = mt * 16 + kq * 4 + rg;
        const float hprev = (s == 0)
            ? h0[(size_t)be * HH + jg]
            : out[((size_t)tp * BB + be) * 2 * HH + dir * HH + jg];
        const float r = 1.f / (1.f + __expf(-(ar[rg] + b_ir + b_hr)));
        const float z = 1.f / (1.f + __expf(-(az[rg] + b_iz + b_hz)));
        const float n = tanhf(ain[rg] + b_in + r * (ahn[rg] + b_hn));
        const float hnew = (1.f - z) * n + z * hprev;
        out[((size_t)t * BB + be) * 2 * HH + dir * HH + jg] = hnew;
        if (s == TT - 1) {
            float* hT = out + (size_t)TT * BB * 2 * HH + (size_t)dir * BB * HH;
            hT[(size_t)be * HH + jg] = hnew;
        }
    }
}

extern "C" void kernel_launch(void* const* d_in, const int* in_sizes, int n_in,
                              void* d_out, int out_size, void* d_ws, size_t ws_size,
                              hipStream_t stream) {
    (void)in_sizes; (void)n_in; (void)out_size;

    const float* inp   = (const float*)d_in[0];
    const float* h0f   = (const float*)d_in[1];
    const float* h0b   = (const float*)d_in[2];
    const float* Wih_f = (const float*)d_in[3];
    const float* Whh_f = (const float*)d_in[4];
    const float* bih_f = (const float*)d_in[5];
    const float* bhh_f = (const float*)d_in[6];
    const float* Wih_b = (const float*)d_in[7];
    const float* Whh_b = (const float*)d_in[8];
    const float* bih_b = (const float*)d_in[9];
    const float* bhh_b = (const float*)d_in[10];
    float* out = (float*)d_out;

    const size_t W_BYTES = (size_t)2 * 3 * HH * 1024 * sizeof(unsigned short);  // 6.29 MB
    const bool use_ws = (ws_size >= W_BYTES);
    unsigned short* wsW = (unsigned short*)d_ws;

    const dim3 grid(HH / 16, BB / 16, 2);   // 32 x 4 x 2 = 256 blocks
    const dim3 block(64, 1, 1);

    if (use_ws) {
        convert_w_kernel<<<1024, 256, 0, stream>>>(Wih_f, Whh_f, Wih_b, Whh_b, wsW);
        for (int s = 0; s < TT; ++s) {
            gru_step_kernel<true><<<grid, block, 0, stream>>>(
                inp, h0f, h0b, Wih_f, Whh_f, bih_f, bhh_f,
                Wih_b, Whh_b, bih_b, bhh_b, wsW, out, s);
        }
    } else {
        for (int s = 0; s < TT; ++s) {
            gru_step_kernel<false><<<grid, block, 0, stream>>>(
                inp, h0f, h0b, Wih_f, Whh_f, bih_f, bhh_f,
                Wih_b, Whh_b, bih_b, bhh_b, nullptr, out, s);
        }
    }
}